// Round 1
// baseline (441.027 us; speedup 1.0000x reference)
//
#include <hip/hip_runtime.h>

// IndRNN: h_t = relu(x_t + w * h_{t-1}), per-channel scan.
// T=2048, B=32, H=1024 -> 32768 independent channels, one thread each.
// Memory-bound: 537 MB traffic, floor ~85 us @ 6.3 TB/s.

#define T_STEPS 2048
#define B_DIM   32
#define H_DIM   1024
#define BH      (B_DIM * H_DIM)   // 32768 channels = stride per time step
#define PF      16                // prefetch depth (outstanding loads/thread)

__global__ __launch_bounds__(64, 1)
void indrnn_kernel(const float* __restrict__ x,
                   const float* __restrict__ h0,
                   const float* __restrict__ w,
                   float* __restrict__ out)
{
    const int c = blockIdx.x * 64 + threadIdx.x;   // channel id, 0..BH-1
    const float wv = w[c & (H_DIM - 1)];           // h index = c % H (coalesced)
    float h = h0[c];

    const float* xp = x + c;
    float* op = out + c;

    // Register double-buffer: loads are independent of the recurrence, so we
    // keep PF of them in flight to cover ~900-cycle HBM latency at 2 waves/CU.
    float buf[PF];
#pragma unroll
    for (int i = 0; i < PF; ++i)
        buf[i] = xp[(size_t)i * BH];

    int t0 = 0;
    for (; t0 + PF < T_STEPS; t0 += PF) {
        float nxt[PF];
        const int tn = t0 + PF;
#pragma unroll
        for (int i = 0; i < PF; ++i)
            nxt[i] = xp[(size_t)(tn + i) * BH];

#pragma unroll
        for (int i = 0; i < PF; ++i) {
            h = fmaxf(fmaf(wv, h, buf[i]), 0.0f);
            op[(size_t)(t0 + i) * BH] = h;
        }

#pragma unroll
        for (int i = 0; i < PF; ++i)
            buf[i] = nxt[i];
    }

    // Tail chunk (T divisible by PF: exactly one)
#pragma unroll
    for (int i = 0; i < PF; ++i) {
        h = fmaxf(fmaf(wv, h, buf[i]), 0.0f);
        op[(size_t)(t0 + i) * BH] = h;
    }
}

extern "C" void kernel_launch(void* const* d_in, const int* in_sizes, int n_in,
                              void* d_out, int out_size, void* d_ws, size_t ws_size,
                              hipStream_t stream) {
    const float* x  = (const float*)d_in[0];  // (T, B, H)
    const float* h0 = (const float*)d_in[1];  // (B, H)
    const float* w  = (const float*)d_in[2];  // (H,)
    float* out = (float*)d_out;               // (T, B, H)

    indrnn_kernel<<<BH / 64, 64, 0, stream>>>(x, h0, w, out);
}

// Round 2
// 422.824 us; speedup vs baseline: 1.0430x; 1.0430x over previous
//
#include <hip/hip_runtime.h>

// IndRNN: h_t = relu(x_t + w * h_{t-1}), per-channel scan over T.
// T=2048, B=32, H=1024 -> 32768 channels. Memory-bound: 537 MB, floor ~85 us.
//
// R1: each thread owns TWO adjacent channels (float2) -> wave reads 512 B
// contiguous per time step (vs 256 B in R0), PF=32 -> 4 MB in flight
// chip-wide, non-temporal loads/stores (pure streaming, skip L2).

#define T_STEPS 2048
#define B_DIM   32
#define H_DIM   1024
#define BH      (B_DIM * H_DIM)      // 32768 channels
#define BH2     (BH / 2)             // 16384 float2 channel-pairs
#define PF      32                   // prefetch depth (time steps in flight)

typedef float f2 __attribute__((ext_vector_type(2)));

__global__ __launch_bounds__(64, 1)
void indrnn_kernel(const f2* __restrict__ x,
                   const f2* __restrict__ h0,
                   const f2* __restrict__ w,
                   f2* __restrict__ out)
{
    const int c2 = blockIdx.x * 64 + threadIdx.x;   // pair id, 0..BH2-1
    // h index of the pair = (2*c2) % H -> pair index (c2 % (H/2))
    const f2 wv = w[c2 & (H_DIM / 2 - 1)];
    f2 h = h0[c2];

    const f2* xp = x + c2;
    f2* op = out + c2;

    f2 buf[PF];
#pragma unroll
    for (int i = 0; i < PF; ++i)
        buf[i] = __builtin_nontemporal_load(&xp[(size_t)i * BH2]);

    int t0 = 0;
    for (; t0 + PF < T_STEPS; t0 += PF) {
        f2 nxt[PF];
        const int tn = t0 + PF;
#pragma unroll
        for (int i = 0; i < PF; ++i)
            nxt[i] = __builtin_nontemporal_load(&xp[(size_t)(tn + i) * BH2]);

#pragma unroll
        for (int i = 0; i < PF; ++i) {
            h.x = fmaxf(fmaf(wv.x, h.x, buf[i].x), 0.0f);
            h.y = fmaxf(fmaf(wv.y, h.y, buf[i].y), 0.0f);
            __builtin_nontemporal_store(h, &op[(size_t)(t0 + i) * BH2]);
        }

#pragma unroll
        for (int i = 0; i < PF; ++i)
            buf[i] = nxt[i];
    }

    // Tail chunk (T % PF == 0: exactly one)
#pragma unroll
    for (int i = 0; i < PF; ++i) {
        h.x = fmaxf(fmaf(wv.x, h.x, buf[i].x), 0.0f);
        h.y = fmaxf(fmaf(wv.y, h.y, buf[i].y), 0.0f);
        __builtin_nontemporal_store(h, &op[(size_t)(t0 + i) * BH2]);
    }
}

extern "C" void kernel_launch(void* const* d_in, const int* in_sizes, int n_in,
                              void* d_out, int out_size, void* d_ws, size_t ws_size,
                              hipStream_t stream) {
    const f2* x  = (const f2*)d_in[0];  // (T, B, H)
    const f2* h0 = (const f2*)d_in[1];  // (B, H)
    const f2* w  = (const f2*)d_in[2];  // (H,)
    f2* out = (f2*)d_out;               // (T, B, H)

    indrnn_kernel<<<BH2 / 64, 64, 0, stream>>>(x, h0, w, out);
}